// Round 7
// baseline (186.643 us; speedup 1.0000x reference)
//
#include <hip/hip_runtime.h>
#include <hip/hip_bf16.h>
#include <stdint.h>

// MHA forward: B=4, S=2048, D=1024, H=16, dk=64. fp32 in/out, bf16 MFMA internally.
// Pipeline: cast -> QKV GEMM (bf16, BK=64 swizzled LDS, V written transposed in epilogue)
//           -> causal flash attention (swapped operands, static-max softmax, MERGED q-parts)
//           -> out GEMM.

typedef unsigned short u16;
typedef short bf16x8 __attribute__((ext_vector_type(8)));
typedef float f32x4 __attribute__((ext_vector_type(4)));
typedef unsigned short u16x8 __attribute__((ext_vector_type(8)));

#define S_LEN 2048
#define DMODEL 1024
#define NH 16

__device__ __forceinline__ u16 f2bf(float f) {
    unsigned u = __builtin_bit_cast(unsigned, f);
    unsigned r = (u + 0x7fffu + ((u >> 16) & 1u)) >> 16;
    return (u16)r;
}

__device__ __forceinline__ float fast_exp2(float x) {
    return __builtin_amdgcn_exp2f(x);
}

__device__ __forceinline__ unsigned cvtpk_bf16(float lo, float hi_) {
    unsigned r;
    asm("v_cvt_pk_bf16_f32 %0, %1, %2" : "=v"(r) : "v"(lo), "v"(hi_));
    return r;
}

__device__ __forceinline__ void gll16(const void* g, void* s) {
    __builtin_amdgcn_global_load_lds((const __attribute__((address_space(1))) unsigned*)g,
                                     (__attribute__((address_space(3))) unsigned*)s, 16, 0, 0);
}

// ---------------- cast: fp32 -> bf16, concat QKV weights ----------------
__global__ __launch_bounds__(256) void cast_all(
    const float* __restrict__ x, const float* __restrict__ wq, const float* __restrict__ wk,
    const float* __restrict__ wv, const float* __restrict__ wo,
    u16* __restrict__ xb, u16* __restrict__ wqkv, u16* __restrict__ wob, int nx) {
    const int NW = DMODEL * DMODEL;
    int i4 = (blockIdx.x * 256 + threadIdx.x) * 4;
    const float* src; u16* dst; int off;
    if (i4 < nx)             { src = x;  dst = xb;            off = i4; }
    else if (i4 < nx + NW)   { src = wq; dst = wqkv;          off = i4 - nx; }
    else if (i4 < nx + 2*NW) { src = wk; dst = wqkv + NW;     off = i4 - nx - NW; }
    else if (i4 < nx + 3*NW) { src = wv; dst = wqkv + 2*NW;   off = i4 - nx - 2*NW; }
    else                     { src = wo; dst = wob;           off = i4 - nx - 3*NW; }
    float4 v = *reinterpret_cast<const float4*>(src + off);
    ushort4 o4; o4.x = f2bf(v.x); o4.y = f2bf(v.y); o4.z = f2bf(v.z); o4.w = f2bf(v.w);
    *reinterpret_cast<ushort4*>(dst + off) = o4;
}

// ---------------- GEMM: C[m][n] = sum_k A[m][k]*B[n][k] ----------------
// 128x128 tile, BK=64, swizzled LDS (chunk ^= row&7, applied via pre-swizzled global src).
// If vt != nullptr, n-blocks with n0 >= 2048 (the V projection) are written TRANSPOSED
// to vt[(b*16+h)*64 + d][s] via a per-wave LDS mini-transpose instead of to C.
template <typename OUT>
__global__ __launch_bounds__(256) void gemm_bt(const u16* __restrict__ A, const u16* __restrict__ B,
                                               OUT* __restrict__ C, int M, int N, int K,
                                               int qcols, float qscale, u16* __restrict__ vt) {
    __shared__ u16 As[128 * 64];
    __shared__ u16 Bs[128 * 64];
    __shared__ u16 Ts[4][16 * 72];   // per-wave transpose scratch
    const int m0 = blockIdx.y * 128, n0 = blockIdx.x * 128;
    const int t = threadIdx.x, w = t >> 6, l = t & 63;
    const int hi = l >> 4;
    const int wr = w >> 1, wc = w & 1;
    f32x4 acc[4][4] = {};

    const int lr = l >> 3;                   // row-within-8
    const int lc = l & 7;                    // 16B chunk
    const int gcol = (lc ^ lr) * 8;          // pre-swizzled source column (elements)
    const u16* Ag = A + (size_t)(m0 + w * 32 + lr) * K + gcol;
    const u16* Bg = B + (size_t)(n0 + w * 32 + lr) * K + gcol;

    for (int k0 = 0; k0 < K; k0 += 64) {
        __syncthreads();
#pragma unroll
        for (int c = 0; c < 4; c++) {
            gll16(Ag + (size_t)c * 8 * K + k0, As + w * 2048 + c * 512);
            gll16(Bg + (size_t)c * 8 * K + k0, Bs + w * 2048 + c * 512);
        }
        __syncthreads();
#pragma unroll
        for (int kk = 0; kk < 2; kk++) {
            bf16x8 af[4], bfr[4];
#pragma unroll
            for (int mi = 0; mi < 4; mi++)
                af[mi] = *(const bf16x8*)&As[(wr * 64 + mi * 16 + (l & 15)) * 64 +
                                             (((kk * 4 + hi) ^ (l & 7)) * 8)];
#pragma unroll
            for (int ni = 0; ni < 4; ni++)
                bfr[ni] = *(const bf16x8*)&Bs[(wc * 64 + ni * 16 + (l & 15)) * 64 +
                                              (((kk * 4 + hi) ^ (l & 7)) * 8)];
#pragma unroll
            for (int mi = 0; mi < 4; mi++)
#pragma unroll
                for (int ni = 0; ni < 4; ni++)
                    acc[mi][ni] = __builtin_amdgcn_mfma_f32_16x16x32_bf16(af[mi], bfr[ni], acc[mi][ni], 0, 0, 0);
        }
    }

    if (vt != nullptr && n0 >= 2048) {
        const int mw = m0 + wr * 64;
        const int bq = mw >> 11;
        const int s0w = mw & (S_LEN - 1);
        const int hd = ((n0 + wc * 64) - 2048) >> 6;
        u16* tb = &Ts[w][0];
#pragma unroll
        for (int ni = 0; ni < 4; ni++) {
#pragma unroll
            for (int mi = 0; mi < 4; mi++) {
                uint2 pk = make_uint2(cvtpk_bf16(acc[mi][ni][0], acc[mi][ni][1]),
                                      cvtpk_bf16(acc[mi][ni][2], acc[mi][ni][3]));
                *(uint2*)&tb[(l & 15) * 72 + mi * 16 + hi * 4] = pk;
            }
            bf16x8 r0 = *(const bf16x8*)&tb[(l & 15) * 72 + hi * 16];
            bf16x8 r1 = *(const bf16x8*)&tb[(l & 15) * 72 + hi * 16 + 8];
            size_t vrow = ((size_t)(bq * 16 + hd) * 64 + ni * 16 + (l & 15)) * S_LEN + s0w + hi * 16;
            *(u16x8*)&vt[vrow]     = (u16x8)r0;
            *(u16x8*)&vt[vrow + 8] = (u16x8)r1;
        }
    } else {
#pragma unroll
        for (int mi = 0; mi < 4; mi++)
#pragma unroll
            for (int ni = 0; ni < 4; ni++)
#pragma unroll
                for (int j = 0; j < 4; j++) {
                    int r = m0 + wr * 64 + mi * 16 + hi * 4 + j;
                    int c = n0 + wc * 64 + ni * 16 + (l & 15);
                    float v = acc[mi][ni][j];
                    if (c < qcols) v *= qscale;
                    if constexpr (__is_same(OUT, u16)) C[(size_t)r * N + c] = f2bf(v);
                    else                               C[(size_t)r * N + c] = v;
                }
    }
}

// ---------------- causal flash attention: merged q-parts ----------------
// Block handles q-parts {p, 15-p} in ONE merged KV sweep: K/V staged once per tile and
// fragment-read once, serving both parts' MFMAs. Part0 active only while tt < nt0.
// S^T = mfma(K, Q): C[key][q]; static-max P = exp2(s-8); O^T = mfma(V^T, P).
__global__ __launch_bounds__(512, 4) void attn(const u16* __restrict__ QKV, const u16* __restrict__ VT,
                                               u16* __restrict__ O) {
    const int bh = blockIdx.x, p = blockIdx.y;
    const int b = bh >> 4, h = bh & 15;
    const int t = threadIdx.x, w = t >> 6, l = t & 63;
    const int q = l & 15, hi = l >> 4, s7 = q & 7;

    __shared__ u16 SM[2][2][64][64];     // [cur][K/V][row][col]   32 KB
    __shared__ u16 PS[8][2][16][64];     // per-wave P, per part    32 KB

    const int srow = t >> 3, sblk = t & 7;
    const int gs = (sblk ^ (srow & 7)) * 8;                // pre-swizzled global source
    const u16* Kg = QKV + (size_t)(b * S_LEN + srow) * 3072 + 1024 + h * 64 + gs;
    const u16* Vg = VT + (size_t)(bh * 64 + srow) * S_LEN + gs;

    const int kA0 = q * 128 + ((hi ^ s7) << 4);            // kk=0; kk=1 is ^64
    const int kA1 = kA0 ^ 64;
    const char* smbase = (const char*)&SM[0][0][0][0];

    char* pb0 = (char*)&PS[w][0][0][0];
    char* pb1 = (char*)&PS[w][1][0][0];
    const int pw0 = q * 128 + ((((0 * 2) + (hi >> 1)) ^ s7) << 4) + ((hi & 1) << 3);
    const int pw1 = q * 128 + ((((1 * 2) + (hi >> 1)) ^ s7) << 4) + ((hi & 1) << 3);
    const int pw2 = q * 128 + ((((2 * 2) + (hi >> 1)) ^ s7) << 4) + ((hi & 1) << 3);
    const int pw3 = q * 128 + ((((3 * 2) + (hi >> 1)) ^ s7) << 4) + ((hi & 1) << 3);
    const int pr0 = q * 128 + (((0 * 4 + hi) ^ s7) << 4);
    const int pr1 = q * 128 + (((1 * 4 + hi) ^ s7) << 4);

    const int part1 = 15 - p;
    const int q128_0 = p * 128, q128_1 = part1 * 128;
    const int nt0 = 2 * p + 2, nt1 = 2 * part1 + 2;       // nt1 >= nt0 for p<=7
    const int qglob0 = q128_0 + w * 16 + q;
    const int qglob1 = q128_1 + w * 16 + q;

    bf16x8 qf0[2], qf1[2];
#pragma unroll
    for (int kk = 0; kk < 2; kk++) {
        qf0[kk] = *(const bf16x8*)&QKV[(size_t)(b * S_LEN + qglob0) * 3072 + h * 64 + kk * 32 + hi * 8];
        qf1[kk] = *(const bf16x8*)&QKV[(size_t)(b * S_LEN + qglob1) * 3072 + h * 64 + kk * 32 + hi * 8];
    }

    f32x4 oacc0[4] = {}, oacc1[4] = {};
    float ssA = 0.f, ssB = 0.f;

    gll16(Kg, (u16*)&SM[0][0][0][0] + t * 8);
    gll16(Vg, (u16*)&SM[0][1][0][0] + t * 8);
    __syncthreads();

    const u16* KgT = Kg + (size_t)64 * 3072;
    const u16* VgT = Vg + 64;

    // per-part softmax: mask, exp2(s-8), row-sum accumulate, P pack -> LDS -> frag regs
    auto softmax_part = [&](f32x4* sacc, int qglob, int kv0, char* pb, float& ss,
                            bf16x8& pf0_, bf16x8& pf1_) {
        const int r0 = qglob - kv0;
        if (r0 < 63) {
            const int rth = r0 - hi * 4;
#pragma unroll
            for (int ni = 0; ni < 4; ni++)
#pragma unroll
                for (int j = 0; j < 4; j++)
                    if (ni * 16 + j > rth) sacc[ni][j] = -1e30f;
        }
        float pv[4][4];
#pragma unroll
        for (int ni = 0; ni < 4; ni++)
#pragma unroll
            for (int j = 0; j < 4; j++) pv[ni][j] = fast_exp2(sacc[ni][j] - 8.0f);
        ss += ((pv[0][0] + pv[0][1]) + (pv[0][2] + pv[0][3]))
            + ((pv[1][0] + pv[1][1]) + (pv[1][2] + pv[1][3]))
            + ((pv[2][0] + pv[2][1]) + (pv[2][2] + pv[2][3]))
            + ((pv[3][0] + pv[3][1]) + (pv[3][2] + pv[3][3]));
        *(uint2*)(pb + pw0) = make_uint2(cvtpk_bf16(pv[0][0], pv[0][1]), cvtpk_bf16(pv[0][2], pv[0][3]));
        *(uint2*)(pb + pw1) = make_uint2(cvtpk_bf16(pv[1][0], pv[1][1]), cvtpk_bf16(pv[1][2], pv[1][3]));
        *(uint2*)(pb + pw2) = make_uint2(cvtpk_bf16(pv[2][0], pv[2][1]), cvtpk_bf16(pv[2][2], pv[2][3]));
        *(uint2*)(pb + pw3) = make_uint2(cvtpk_bf16(pv[3][0], pv[3][1]), cvtpk_bf16(pv[3][2], pv[3][3]));
        pf0_ = *(const bf16x8*)(pb + pr0);
        pf1_ = *(const bf16x8*)(pb + pr1);
    };

#pragma unroll 1
    for (int tt = 0; tt < nt1; ++tt) {
        const int cur = tt & 1;
        if (tt + 1 < nt1) {
            gll16(KgT, (u16*)&SM[cur ^ 1][0][0][0] + t * 8);
            gll16(VgT, (u16*)&SM[cur ^ 1][1][0][0] + t * 8);
            KgT += (size_t)64 * 3072;
            VgT += 64;
        }
        const int kv0 = tt * 64;
        const bool act0 = (tt < nt0) && (q128_0 + w * 16 + 15 >= kv0);
        const bool act1 = (q128_1 + w * 16 + 15 >= kv0);
        if (act0 || act1) {
            const char* kb = smbase + cur * 16384;
            f32x4 sacc0[4] = {}, sacc1[4] = {};
            __builtin_amdgcn_s_setprio(1);
#pragma unroll
            for (int kk = 0; kk < 2; kk++) {
                const char* ka = kb + (kk ? kA1 : kA0);
                bf16x8 kfr[4];
#pragma unroll
                for (int ni = 0; ni < 4; ni++) kfr[ni] = *(const bf16x8*)(ka + ni * 2048);
                if (act0) {
#pragma unroll
                    for (int ni = 0; ni < 4; ni++)
                        sacc0[ni] = __builtin_amdgcn_mfma_f32_16x16x32_bf16(kfr[ni], qf0[kk], sacc0[ni], 0, 0, 0);
                }
                if (act1) {
#pragma unroll
                    for (int ni = 0; ni < 4; ni++)
                        sacc1[ni] = __builtin_amdgcn_mfma_f32_16x16x32_bf16(kfr[ni], qf1[kk], sacc1[ni], 0, 0, 0);
                }
            }
            __builtin_amdgcn_s_setprio(0);
            bf16x8 pf00, pf01, pf10, pf11;
            if (act0) softmax_part(sacc0, qglob0, kv0, pb0, ssA, pf00, pf01);
            if (act1) softmax_part(sacc1, qglob1, kv0, pb1, ssB, pf10, pf11);
            const char* vb = kb + 8192;
            __builtin_amdgcn_s_setprio(1);
#pragma unroll
            for (int kk = 0; kk < 2; kk++) {
                const char* va = vb + (kk ? kA1 : kA0);
                bf16x8 vfr[4];
#pragma unroll
                for (int di = 0; di < 4; di++) vfr[di] = *(const bf16x8*)(va + di * 2048);
                if (act0) {
                    bf16x8 pf = kk ? pf01 : pf00;
#pragma unroll
                    for (int di = 0; di < 4; di++)
                        oacc0[di] = __builtin_amdgcn_mfma_f32_16x16x32_bf16(vfr[di], pf, oacc0[di], 0, 0, 0);
                }
                if (act1) {
                    bf16x8 pf = kk ? pf11 : pf10;
#pragma unroll
                    for (int di = 0; di < 4; di++)
                        oacc1[di] = __builtin_amdgcn_mfma_f32_16x16x32_bf16(vfr[di], pf, oacc1[di], 0, 0, 0);
                }
            }
            __builtin_amdgcn_s_setprio(0);
        }
        __syncthreads();
    }

    // epilogue: normalize and store both parts
    {
        float ssr = ssA;
        ssr += __shfl_xor(ssr, 16, 64);
        ssr += __shfl_xor(ssr, 32, 64);
        float inv = 1.0f / ssr;
#pragma unroll
        for (int di = 0; di < 4; di++) {
            ushort4 o4;
            o4.x = f2bf(oacc0[di][0] * inv);
            o4.y = f2bf(oacc0[di][1] * inv);
            o4.z = f2bf(oacc0[di][2] * inv);
            o4.w = f2bf(oacc0[di][3] * inv);
            *(ushort4*)&O[(size_t)(b * S_LEN + qglob0) * DMODEL + h * 64 + di * 16 + hi * 4] = o4;
        }
    }
    {
        float ssr = ssB;
        ssr += __shfl_xor(ssr, 16, 64);
        ssr += __shfl_xor(ssr, 32, 64);
        float inv = 1.0f / ssr;
#pragma unroll
        for (int di = 0; di < 4; di++) {
            ushort4 o4;
            o4.x = f2bf(oacc1[di][0] * inv);
            o4.y = f2bf(oacc1[di][1] * inv);
            o4.z = f2bf(oacc1[di][2] * inv);
            o4.w = f2bf(oacc1[di][3] * inv);
            *(ushort4*)&O[(size_t)(b * S_LEN + qglob1) * DMODEL + h * 64 + di * 16 + hi * 4] = o4;
        }
    }
}

extern "C" void kernel_launch(void* const* d_in, const int* in_sizes, int n_in,
                              void* d_out, int out_size, void* d_ws, size_t ws_size,
                              hipStream_t stream) {
    const float* x  = (const float*)d_in[0];
    const float* wq = (const float*)d_in[1];
    const float* wk = (const float*)d_in[2];
    const float* wv = (const float*)d_in[3];
    const float* wo = (const float*)d_in[4];
    const int nx = in_sizes[0];              // 8388608 = 4*2048*1024
    const int BS = nx / DMODEL;              // 8192
    const int NW = DMODEL * DMODEL;

    u16* xb   = (u16*)d_ws;                  // [8192][1024]
    u16* wqkv = xb + (size_t)nx;             // [3072][1024]
    u16* wob  = wqkv + (size_t)3 * NW;       // [1024][1024]
    u16* qkv  = wob + (size_t)NW;            // [8192][3072] (V region unused)
    u16* vt   = qkv + (size_t)BS * 3072;     // [B*H*64][2048]
    u16* ob   = vt + (size_t)nx;             // [8192][1024]

    int ncast = (nx + 4 * NW) / 4 / 256;
    cast_all<<<ncast, 256, 0, stream>>>(x, wq, wk, wv, wo, xb, wqkv, wob, nx);

    const float QSC = 0.125f * 1.44269504088896f;   // 1/sqrt(dk) * log2(e)
    gemm_bt<u16><<<dim3(3072 / 128, BS / 128), 256, 0, stream>>>(xb, wqkv, qkv, BS, 3072, DMODEL,
                                                                 DMODEL, QSC, vt);

    attn<<<dim3((BS / S_LEN) * NH, 8), 512, 0, stream>>>(qkv, vt, ob);

    gemm_bt<float><<<dim3(DMODEL / 128, BS / 128), 256, 0, stream>>>(ob, wob, (float*)d_out, BS, DMODEL, DMODEL,
                                                                     0, 1.0f, nullptr);
}

// Round 8
// 160.777 us; speedup vs baseline: 1.1609x; 1.1609x over previous
//
#include <hip/hip_runtime.h>
#include <hip/hip_bf16.h>
#include <stdint.h>

// MHA forward: B=4, S=2048, D=1024, H=16, dk=64. fp32 in/out, bf16 MFMA internally.
// Pipeline: cast -> QKV GEMM (bf16, BK=64 swizzled LDS, V written transposed in epilogue)
//           -> causal flash attention (swapped operands, static-max softmax,
//              one 64-row q-tile per 4-wave block, 512 blocks) -> out GEMM.

typedef unsigned short u16;
typedef short bf16x8 __attribute__((ext_vector_type(8)));
typedef float f32x4 __attribute__((ext_vector_type(4)));
typedef unsigned short u16x8 __attribute__((ext_vector_type(8)));

#define S_LEN 2048
#define DMODEL 1024
#define NH 16

__device__ __forceinline__ u16 f2bf(float f) {
    unsigned u = __builtin_bit_cast(unsigned, f);
    unsigned r = (u + 0x7fffu + ((u >> 16) & 1u)) >> 16;
    return (u16)r;
}

__device__ __forceinline__ float fast_exp2(float x) {
    return __builtin_amdgcn_exp2f(x);
}

__device__ __forceinline__ unsigned cvtpk_bf16(float lo, float hi_) {
    unsigned r;
    asm("v_cvt_pk_bf16_f32 %0, %1, %2" : "=v"(r) : "v"(lo), "v"(hi_));
    return r;
}

__device__ __forceinline__ void gll16(const void* g, void* s) {
    __builtin_amdgcn_global_load_lds((const __attribute__((address_space(1))) unsigned*)g,
                                     (__attribute__((address_space(3))) unsigned*)s, 16, 0, 0);
}

// ---------------- cast: fp32 -> bf16, concat QKV weights ----------------
__global__ __launch_bounds__(256) void cast_all(
    const float* __restrict__ x, const float* __restrict__ wq, const float* __restrict__ wk,
    const float* __restrict__ wv, const float* __restrict__ wo,
    u16* __restrict__ xb, u16* __restrict__ wqkv, u16* __restrict__ wob, int nx) {
    const int NW = DMODEL * DMODEL;
    int i4 = (blockIdx.x * 256 + threadIdx.x) * 4;
    const float* src; u16* dst; int off;
    if (i4 < nx)             { src = x;  dst = xb;            off = i4; }
    else if (i4 < nx + NW)   { src = wq; dst = wqkv;          off = i4 - nx; }
    else if (i4 < nx + 2*NW) { src = wk; dst = wqkv + NW;     off = i4 - nx - NW; }
    else if (i4 < nx + 3*NW) { src = wv; dst = wqkv + 2*NW;   off = i4 - nx - 2*NW; }
    else                     { src = wo; dst = wob;           off = i4 - nx - 3*NW; }
    float4 v = *reinterpret_cast<const float4*>(src + off);
    ushort4 o4; o4.x = f2bf(v.x); o4.y = f2bf(v.y); o4.z = f2bf(v.z); o4.w = f2bf(v.w);
    *reinterpret_cast<ushort4*>(dst + off) = o4;
}

// ---------------- GEMM: C[m][n] = sum_k A[m][k]*B[n][k] ----------------
// 128x128 tile, BK=64, swizzled LDS (chunk ^= row&7, applied via pre-swizzled global src).
// If vt != nullptr, n-blocks with n0 >= 2048 (the V projection) are written TRANSPOSED
// to vt[(b*16+h)*64 + d][s] via a per-wave LDS mini-transpose instead of to C.
template <typename OUT>
__global__ __launch_bounds__(256) void gemm_bt(const u16* __restrict__ A, const u16* __restrict__ B,
                                               OUT* __restrict__ C, int M, int N, int K,
                                               int qcols, float qscale, u16* __restrict__ vt) {
    __shared__ u16 As[128 * 64];
    __shared__ u16 Bs[128 * 64];
    __shared__ u16 Ts[4][16 * 72];   // per-wave transpose scratch
    const int m0 = blockIdx.y * 128, n0 = blockIdx.x * 128;
    const int t = threadIdx.x, w = t >> 6, l = t & 63;
    const int hi = l >> 4;
    const int wr = w >> 1, wc = w & 1;
    f32x4 acc[4][4] = {};

    const int lr = l >> 3;                   // row-within-8
    const int lc = l & 7;                    // 16B chunk
    const int gcol = (lc ^ lr) * 8;          // pre-swizzled source column (elements)
    const u16* Ag = A + (size_t)(m0 + w * 32 + lr) * K + gcol;
    const u16* Bg = B + (size_t)(n0 + w * 32 + lr) * K + gcol;

    for (int k0 = 0; k0 < K; k0 += 64) {
        __syncthreads();
#pragma unroll
        for (int c = 0; c < 4; c++) {
            gll16(Ag + (size_t)c * 8 * K + k0, As + w * 2048 + c * 512);
            gll16(Bg + (size_t)c * 8 * K + k0, Bs + w * 2048 + c * 512);
        }
        __syncthreads();
#pragma unroll
        for (int kk = 0; kk < 2; kk++) {
            bf16x8 af[4], bfr[4];
#pragma unroll
            for (int mi = 0; mi < 4; mi++)
                af[mi] = *(const bf16x8*)&As[(wr * 64 + mi * 16 + (l & 15)) * 64 +
                                             (((kk * 4 + hi) ^ (l & 7)) * 8)];
#pragma unroll
            for (int ni = 0; ni < 4; ni++)
                bfr[ni] = *(const bf16x8*)&Bs[(wc * 64 + ni * 16 + (l & 15)) * 64 +
                                              (((kk * 4 + hi) ^ (l & 7)) * 8)];
#pragma unroll
            for (int mi = 0; mi < 4; mi++)
#pragma unroll
                for (int ni = 0; ni < 4; ni++)
                    acc[mi][ni] = __builtin_amdgcn_mfma_f32_16x16x32_bf16(af[mi], bfr[ni], acc[mi][ni], 0, 0, 0);
        }
    }

    if (vt != nullptr && n0 >= 2048) {
        const int mw = m0 + wr * 64;
        const int bq = mw >> 11;
        const int s0w = mw & (S_LEN - 1);
        const int hd = ((n0 + wc * 64) - 2048) >> 6;
        u16* tb = &Ts[w][0];
#pragma unroll
        for (int ni = 0; ni < 4; ni++) {
#pragma unroll
            for (int mi = 0; mi < 4; mi++) {
                uint2 pk = make_uint2(cvtpk_bf16(acc[mi][ni][0], acc[mi][ni][1]),
                                      cvtpk_bf16(acc[mi][ni][2], acc[mi][ni][3]));
                *(uint2*)&tb[(l & 15) * 72 + mi * 16 + hi * 4] = pk;
            }
            bf16x8 r0 = *(const bf16x8*)&tb[(l & 15) * 72 + hi * 16];
            bf16x8 r1 = *(const bf16x8*)&tb[(l & 15) * 72 + hi * 16 + 8];
            size_t vrow = ((size_t)(bq * 16 + hd) * 64 + ni * 16 + (l & 15)) * S_LEN + s0w + hi * 16;
            *(u16x8*)&vt[vrow]     = (u16x8)r0;
            *(u16x8*)&vt[vrow + 8] = (u16x8)r1;
        }
    } else {
#pragma unroll
        for (int mi = 0; mi < 4; mi++)
#pragma unroll
            for (int ni = 0; ni < 4; ni++)
#pragma unroll
                for (int j = 0; j < 4; j++) {
                    int r = m0 + wr * 64 + mi * 16 + hi * 4 + j;
                    int c = n0 + wc * 64 + ni * 16 + (l & 15);
                    float v = acc[mi][ni][j];
                    if (c < qcols) v *= qscale;
                    if constexpr (__is_same(OUT, u16)) C[(size_t)r * N + c] = f2bf(v);
                    else                               C[(size_t)r * N + c] = v;
                }
    }
}

// ---------------- causal flash attention: 64-row q-tile per 4-wave block ----------------
// grid (16 bh, 32 y), qt = (y<16) ? y : 47-y  (complementary lengths pair up under
// round-robin dispatch; performance heuristic only). Block = 256 thr / 4 waves, each wave
// owns 16 q-rows. nt = qt+1 KV tiles of 64, double-buffered K/V staging.
// S^T = mfma(K, Q): C[key][q], q = lane&15; static-max P = exp2(s-8) (scores bounded,
// softmax shift-invariant); O^T = mfma(V^T, P); normalize by accumulated row-sum at end.
__global__ __launch_bounds__(256, 2) void attn(const u16* __restrict__ QKV, const u16* __restrict__ VT,
                                               u16* __restrict__ O) {
    const int bh = blockIdx.x, y = blockIdx.y;
    const int qt = (y < 16) ? y : 47 - y;
    const int b = bh >> 4, h = bh & 15;
    const int t = threadIdx.x, w = t >> 6, l = t & 63;
    const int q = l & 15, hi = l >> 4, s7 = q & 7;

    __shared__ u16 SM[2][2][64][64];   // [cur][K/V][row][col]  32 KB
    __shared__ u16 PS[4][16][64];      // per-wave P             8 KB

    // staging: 256 thr x 16B = 4KB; two rounds cover a 64x64 tile (rows 0-31, 32-63)
    const int srow = t >> 3, sblk = t & 7;
    const int gs = (sblk ^ (srow & 7)) * 8;                // pre-swizzled global source
    const u16* Kg = QKV + (size_t)(b * S_LEN + srow) * 3072 + 1024 + h * 64 + gs;
    const u16* Vg = VT + (size_t)(bh * 64 + srow) * S_LEN + gs;
    const u16* Kg2 = Kg + (size_t)32 * 3072;               // rows +32 (row&7 unchanged)
    const u16* Vg2 = Vg + (size_t)32 * S_LEN;

    const int kA0 = q * 128 + ((hi ^ s7) << 4);            // kk=0; kk=1 is ^64
    const int kA1 = kA0 ^ 64;
    const char* smbase = (const char*)&SM[0][0][0][0];

    char* pbase = (char*)&PS[w][0][0];
    const int pw0 = q * 128 + ((((0 * 2) + (hi >> 1)) ^ s7) << 4) + ((hi & 1) << 3);
    const int pw1 = q * 128 + ((((1 * 2) + (hi >> 1)) ^ s7) << 4) + ((hi & 1) << 3);
    const int pw2 = q * 128 + ((((2 * 2) + (hi >> 1)) ^ s7) << 4) + ((hi & 1) << 3);
    const int pw3 = q * 128 + ((((3 * 2) + (hi >> 1)) ^ s7) << 4) + ((hi & 1) << 3);
    const int pr0 = q * 128 + (((0 * 4 + hi) ^ s7) << 4);
    const int pr1 = q * 128 + (((1 * 4 + hi) ^ s7) << 4);

    const int q64 = qt * 64;
    const int nt = qt + 1;
    const int qglob = q64 + w * 16 + q;                    // this lane's q-row

    // Q fragment (B-operand): col = lane&15 = q, k-contig 8 at hi*8
    bf16x8 qf[2];
#pragma unroll
    for (int kk = 0; kk < 2; kk++)
        qf[kk] = *(const bf16x8*)&QKV[(size_t)(b * S_LEN + qglob) * 3072 + h * 64 + kk * 32 + hi * 8];

    f32x4 oacc[4] = {};
    float ss0 = 0.f, ss1 = 0.f;

    gll16(Kg,  (u16*)&SM[0][0][0][0] + t * 8);
    gll16(Kg2, (u16*)&SM[0][0][0][0] + 2048 + t * 8);
    gll16(Vg,  (u16*)&SM[0][1][0][0] + t * 8);
    gll16(Vg2, (u16*)&SM[0][1][0][0] + 2048 + t * 8);
    __syncthreads();

    const u16* KgT  = Kg  + (size_t)64 * 3072;
    const u16* Kg2T = Kg2 + (size_t)64 * 3072;
    const u16* VgT  = Vg  + 64;
    const u16* Vg2T = Vg2 + 64;

#pragma unroll 1
    for (int tt = 0; tt < nt; ++tt) {
        const int cur = tt & 1;
        if (tt + 1 < nt) {
            gll16(KgT,  (u16*)&SM[cur ^ 1][0][0][0] + t * 8);
            gll16(Kg2T, (u16*)&SM[cur ^ 1][0][0][0] + 2048 + t * 8);
            gll16(VgT,  (u16*)&SM[cur ^ 1][1][0][0] + t * 8);
            gll16(Vg2T, (u16*)&SM[cur ^ 1][1][0][0] + 2048 + t * 8);
            KgT  += (size_t)64 * 3072;
            Kg2T += (size_t)64 * 3072;
            VgT  += 64;
            Vg2T += 64;
        }
        const int kv0 = tt * 64;
        const char* kb = smbase + cur * 16384;
        // S^T = K · Q^T  (C[key][q]; key = ni*16 + hi*4 + j, q = lane&15)
        f32x4 sacc[4] = {};
        __builtin_amdgcn_s_setprio(1);
#pragma unroll
        for (int kk = 0; kk < 2; kk++) {
            const char* ka = kb + (kk ? kA1 : kA0);
#pragma unroll
            for (int ni = 0; ni < 4; ni++) {
                bf16x8 kf = *(const bf16x8*)(ka + ni * 2048);
                sacc[ni] = __builtin_amdgcn_mfma_f32_16x16x32_bf16(kf, qf[kk], sacc[ni], 0, 0, 0);
            }
        }
        __builtin_amdgcn_s_setprio(0);
        // causal mask (diagonal tile only: kv0 == q64)
        const int r0 = qglob - kv0;
        if (r0 < 63) {
            const int rth = r0 - hi * 4;
#pragma unroll
            for (int ni = 0; ni < 4; ni++)
#pragma unroll
                for (int j = 0; j < 4; j++)
                    if (ni * 16 + j > rth) sacc[ni][j] = -1e30f;
        }
        // P = exp2(s - 8); per-lane row-sum accumulates across tiles
        float pv[4][4];
#pragma unroll
        for (int ni = 0; ni < 4; ni++)
#pragma unroll
            for (int j = 0; j < 4; j++) pv[ni][j] = fast_exp2(sacc[ni][j] - 8.0f);
        ss0 += ((pv[0][0] + pv[0][1]) + (pv[0][2] + pv[0][3]))
             + ((pv[1][0] + pv[1][1]) + (pv[1][2] + pv[1][3]));
        ss1 += ((pv[2][0] + pv[2][1]) + (pv[2][2] + pv[2][3]))
             + ((pv[3][0] + pv[3][1]) + (pv[3][2] + pv[3][3]));
        *(uint2*)(pbase + pw0) = make_uint2(cvtpk_bf16(pv[0][0], pv[0][1]), cvtpk_bf16(pv[0][2], pv[0][3]));
        *(uint2*)(pbase + pw1) = make_uint2(cvtpk_bf16(pv[1][0], pv[1][1]), cvtpk_bf16(pv[1][2], pv[1][3]));
        *(uint2*)(pbase + pw2) = make_uint2(cvtpk_bf16(pv[2][0], pv[2][1]), cvtpk_bf16(pv[2][2], pv[2][3]));
        *(uint2*)(pbase + pw3) = make_uint2(cvtpk_bf16(pv[3][0], pv[3][1]), cvtpk_bf16(pv[3][2], pv[3][3]));
        bf16x8 pf0 = *(const bf16x8*)(pbase + pr0);
        bf16x8 pf1 = *(const bf16x8*)(pbase + pr1);
        // O^T += V^T · P^T  (C[d][q]; d = di*16 + hi*4 + j, q = lane&15)
        const char* vb = kb + 8192;
        __builtin_amdgcn_s_setprio(1);
#pragma unroll
        for (int kk = 0; kk < 2; kk++) {
            const char* va = vb + (kk ? kA1 : kA0);
            bf16x8 pf = kk ? pf1 : pf0;
#pragma unroll
            for (int di = 0; di < 4; di++) {
                bf16x8 vf = *(const bf16x8*)(va + di * 2048);
                oacc[di] = __builtin_amdgcn_mfma_f32_16x16x32_bf16(vf, pf, oacc[di], 0, 0, 0);
            }
        }
        __builtin_amdgcn_s_setprio(0);
        __syncthreads();
    }

    // row-sum across the 4 hi-groups (lanes q, q+16, q+32, q+48), then normalize
    float ssr = ss0 + ss1;
    ssr += __shfl_xor(ssr, 16, 64);
    ssr += __shfl_xor(ssr, 32, 64);
    float inv = 1.0f / ssr;
#pragma unroll
    for (int di = 0; di < 4; di++) {
        ushort4 o4;
        o4.x = f2bf(oacc[di][0] * inv);
        o4.y = f2bf(oacc[di][1] * inv);
        o4.z = f2bf(oacc[di][2] * inv);
        o4.w = f2bf(oacc[di][3] * inv);
        *(ushort4*)&O[(size_t)(b * S_LEN + qglob) * DMODEL + h * 64 + di * 16 + hi * 4] = o4;
    }
}

extern "C" void kernel_launch(void* const* d_in, const int* in_sizes, int n_in,
                              void* d_out, int out_size, void* d_ws, size_t ws_size,
                              hipStream_t stream) {
    const float* x  = (const float*)d_in[0];
    const float* wq = (const float*)d_in[1];
    const float* wk = (const float*)d_in[2];
    const float* wv = (const float*)d_in[3];
    const float* wo = (const float*)d_in[4];
    const int nx = in_sizes[0];              // 8388608 = 4*2048*1024
    const int BS = nx / DMODEL;              // 8192
    const int NW = DMODEL * DMODEL;

    u16* xb   = (u16*)d_ws;                  // [8192][1024]
    u16* wqkv = xb + (size_t)nx;             // [3072][1024]
    u16* wob  = wqkv + (size_t)3 * NW;       // [1024][1024]
    u16* qkv  = wob + (size_t)NW;            // [8192][3072] (V region unused)
    u16* vt   = qkv + (size_t)BS * 3072;     // [B*H*64][2048]
    u16* ob   = vt + (size_t)nx;             // [8192][1024]

    int ncast = (nx + 4 * NW) / 4 / 256;
    cast_all<<<ncast, 256, 0, stream>>>(x, wq, wk, wv, wo, xb, wqkv, wob, nx);

    const float QSC = 0.125f * 1.44269504088896f;   // 1/sqrt(dk) * log2(e)
    gemm_bt<u16><<<dim3(3072 / 128, BS / 128), 256, 0, stream>>>(xb, wqkv, qkv, BS, 3072, DMODEL,
                                                                 DMODEL, QSC, vt);

    attn<<<dim3((BS / S_LEN) * NH, 32), 256, 0, stream>>>(qkv, vt, ob);

    gemm_bt<float><<<dim3(DMODEL / 128, BS / 128), 256, 0, stream>>>(ob, wob, (float*)d_out, BS, DMODEL, DMODEL,
                                                                     0, 1.0f, nullptr);
}